// Round 6
// baseline (230.615 us; speedup 1.0000x reference)
//
#include <hip/hip_runtime.h>
#include <hip/hip_bf16.h>

#define BATCH 16
#define SEQL  4096
#define NH    16
#define HD    64
#define HID   1024
#define NCHUNK 8
#define CHUNK  (SEQL / NCHUNK)   // 512
#define KV_ELEMS (BATCH * NH * SEQL * HD)  // 67108864
#define PSTRIDE 68               // partial record: [0]=L, [1..64]=A
#define C2 0.1803368801f         // 0.125 * log2(e)

typedef float f4 __attribute__((ext_vector_type(4)));

// ---------------------------------------------------------------------------
// Kernel 1: single-pass batched GEMV.  out[w][b][o] = x[b][:] . W[o][:] + bias
// ---------------------------------------------------------------------------
__global__ __launch_bounds__(256) void gemv3(
    const float* __restrict__ x,
    const float* __restrict__ W0, const float* __restrict__ W1,
    const float* __restrict__ W2,
    const float* __restrict__ b0, const float* __restrict__ b1,
    const float* __restrict__ b2,
    float* __restrict__ out)
{
    __shared__ float xs[BATCH * HID];
    const int t = threadIdx.x;
    {
        const f4* src = (const f4*)x;
        f4* dst = (f4*)xs;
        #pragma unroll
        for (int i = 0; i < (BATCH * HID / 4) / 256; ++i)
            dst[t + i * 256] = src[t + i * 256];
    }
    __syncthreads();

    const int which = blockIdx.x >> 8;
    const int ob    = (blockIdx.x & 255) << 2;
    const float* W    = (which == 0) ? W0 : ((which == 1) ? W1 : W2);
    const float* bias = (which == 0) ? b0 : ((which == 1) ? b1 : b2);
    const int col = t >> 6, lane = t & 63;
    const int o = ob + col;
    const float* wrow = W + (size_t)o * HID;

    float acc[BATCH];
    #pragma unroll
    for (int b = 0; b < BATCH; ++b) acc[b] = 0.f;

    #pragma unroll
    for (int i = 0; i < 4; ++i) {
        const int k = (lane << 2) + (i << 8);
        const f4 w4 = *(const f4*)&wrow[k];
        #pragma unroll
        for (int b = 0; b < BATCH; ++b) {
            const f4 h4 = *(const f4*)&xs[b * HID + k];
            acc[b] += w4.x * h4.x + w4.y * h4.y + w4.z * h4.z + w4.w * h4.w;
        }
    }

    #pragma unroll
    for (int b = 0; b < BATCH; ++b) {
        #pragma unroll
        for (int sh = 1; sh < 64; sh <<= 1)
            acc[b] += __shfl_xor(acc[b], sh);
    }
    if (lane == 0) {
        const float bb = bias[o];
        #pragma unroll
        for (int b = 0; b < BATCH; ++b)
            out[which * (BATCH * HID) + b * HID + o] = acc[b] + bb;
    }
}

// ---------------------------------------------------------------------------
// Kernel 2: fused cache-copy + flash-decode partial attention.
//   grid = (256 (b,h), 8 L-chunks), block = 256 (16 groups x 16 lanes).
//   nt LOADS (no L2 allocate on the streamed reads) + PLAIN stores (writes
//   aggregate in L2 and evict as long sequential bursts — the fill path).
//   Row `pos` is streamed STALE and corrected exactly in merge_fix.
// ---------------------------------------------------------------------------
__global__ __launch_bounds__(256, 6) void attn_fused(
    const float* __restrict__ qkv,     // q @0
    const float* __restrict__ past_k,
    const float* __restrict__ past_v,
    const float* __restrict__ mask,    // [16][4096]
    float* __restrict__ kout,
    float* __restrict__ vout,
    float* __restrict__ part)          // [256][8][PSTRIDE]
{
    const int bh = blockIdx.x;         // 0..255
    const int c  = blockIdx.y;         // 0..7
    const int b  = bh >> 4;
    const int h  = bh & 15;
    const int t  = threadIdx.x;
    const int g  = t >> 4;             // group 0..15
    const int j  = t & 15;             // lane in group

    const f4 q4 = *(const f4*)&qkv[b * HID + h * HD + (j << 2)];

    const size_t base = (size_t)bh * (SEQL * HD);
    const float* __restrict__ pkb = past_k + base;
    const float* __restrict__ pvb = past_v + base;
    float* __restrict__ kob = kout + base;
    float* __restrict__ vob = vout + base;
    const float* __restrict__ mrow = mask + b * SEQL;

    float l = 0.f;
    f4 a4 = {0.f, 0.f, 0.f, 0.f};

    #pragma unroll 1
    for (int s = 0; s < CHUNK / 128; ++s) {   // 4 sub-phases of 128 rows
        const int r0 = c * CHUNK + s * 128 + g;       // rows r0 + u*16
        const int o0 = r0 * HD + (j << 2);

        // ---- K phase: stream copy + scores ----
        f4 kx[8];
        float am[8];
        #pragma unroll
        for (int u = 0; u < 8; ++u)
            kx[u] = __builtin_nontemporal_load((const f4*)(pkb + o0 + u * (16 * HD)));
        #pragma unroll
        for (int u = 0; u < 8; ++u)
            am[u] = mrow[r0 + u * 16];
        #pragma unroll
        for (int u = 0; u < 8; ++u)
            *(f4*)(kob + o0 + u * (16 * HD)) = kx[u];

        float p[8];
        #pragma unroll
        for (int u = 0; u < 8; ++u) {
            float d = kx[u].x * q4.x + kx[u].y * q4.y
                    + kx[u].z * q4.z + kx[u].w * q4.w;
            d += __shfl_xor(d, 1);
            d += __shfl_xor(d, 2);
            d += __shfl_xor(d, 4);
            d += __shfl_xor(d, 8);
            float pe = exp2f(d * C2);
            p[u] = (am[u] > 0.f) ? pe : 0.f;
            l += p[u];
        }

        // ---- V phase: stream copy + weighted accumulate ----
        f4 vx[8];
        #pragma unroll
        for (int u = 0; u < 8; ++u)
            vx[u] = __builtin_nontemporal_load((const f4*)(pvb + o0 + u * (16 * HD)));
        #pragma unroll
        for (int u = 0; u < 8; ++u)
            *(f4*)(vob + o0 + u * (16 * HD)) = vx[u];
        #pragma unroll
        for (int u = 0; u < 8; ++u) {
            a4.x += p[u] * vx[u].x;
            a4.y += p[u] * vx[u].y;
            a4.z += p[u] * vx[u].z;
            a4.w += p[u] * vx[u].w;
        }
    }

    // merge the 16 group states (straight sums — fixed-shift softmax)
    __shared__ float sl_[16];
    __shared__ float sa[16][64];
    if (j == 0) sl_[g] = l;
    *(f4*)&sa[g][(j << 2)] = a4;
    __syncthreads();

    float* pr = part + ((size_t)bh * NCHUNK + c) * PSTRIDE;
    if (t < 64) {
        float A = 0.f;
        #pragma unroll
        for (int gg = 0; gg < 16; ++gg) A += sa[gg][t];
        pr[1 + t] = A;
    } else if (t == 64) {
        float L = 0.f;
        #pragma unroll
        for (int gg = 0; gg < 16; ++gg) L += sl_[gg];
        pr[0] = L;
    }
}

// ---------------------------------------------------------------------------
// Kernel 3: per (b,h): overwrite cache row `pos` with the new k/v, correct
//           the affected chunk partial, then merge chunk partials -> ctx.
// ---------------------------------------------------------------------------
__global__ __launch_bounds__(64) void merge_fix(
    const float* __restrict__ qkv,
    const float* __restrict__ past_k,
    const float* __restrict__ past_v,
    const float* __restrict__ mask,
    const int*   __restrict__ cpos,
    float* __restrict__ kout,
    float* __restrict__ vout,
    const float* __restrict__ part,
    float* __restrict__ ctx)
{
    const int bh = blockIdx.x;
    const int b = bh >> 4, h = bh & 15;
    const int t = threadIdx.x;          // 0..63 (= head dim)
    const int pos = cpos[b];

    const size_t rowoff = (size_t)bh * (SEQL * HD) + (size_t)pos * HD + t;
    const int qo = b * HID + h * HD + t;
    const float qd  = qkv[qo];
    const float knd = qkv[BATCH * HID + qo];
    const float vnd = qkv[2 * BATCH * HID + qo];
    const float ksd = past_k[rowoff];
    const float vsd = past_v[rowoff];

    kout[rowoff] = knd;
    vout[rowoff] = vnd;

    float dst = qd * ksd, dnw = qd * knd;
    #pragma unroll
    for (int sh = 1; sh < 64; sh <<= 1) {
        dst += __shfl_xor(dst, sh);
        dnw += __shfl_xor(dnw, sh);
    }
    const float am = mask[b * SEQL + pos];
    float ps = 0.f, pn = 0.f;
    if (am > 0.f) { ps = exp2f(dst * C2); pn = exp2f(dnw * C2); }

    const int cc0 = pos / CHUNK;
    float L = 0.f, A = 0.f;
    #pragma unroll
    for (int cc = 0; cc < NCHUNK; ++cc) {
        const float* pr = part + ((size_t)bh * NCHUNK + cc) * PSTRIDE;
        float Lc = pr[0];
        float Ac = pr[1 + t];
        if (cc == cc0) { Lc += pn - ps; Ac += pn * vnd - ps * vsd; }
        L += Lc;
        A += Ac;
    }
    ctx[bh * HD + t] = A / L;
}

extern "C" void kernel_launch(void* const* d_in, const int* in_sizes, int n_in,
                              void* d_out, int out_size, void* d_ws, size_t ws_size,
                              hipStream_t stream) {
    const float* hs   = (const float*)d_in[0];
    const float* pk   = (const float*)d_in[1];
    const float* pv   = (const float*)d_in[2];
    const float* mask = (const float*)d_in[3];
    const int*   cpos = (const int*)d_in[4];
    const float* Wq   = (const float*)d_in[5];
    const float* bq   = (const float*)d_in[6];
    const float* Wk   = (const float*)d_in[7];
    const float* bk   = (const float*)d_in[8];
    const float* Wv   = (const float*)d_in[9];
    const float* bv   = (const float*)d_in[10];
    const float* Wo   = (const float*)d_in[11];
    const float* bo   = (const float*)d_in[12];

    float* out_attn = (float*)d_out;                 // 16384
    float* kout = out_attn + BATCH * HID;
    float* vout = kout + KV_ELEMS;

    float* ws    = (float*)d_ws;
    float* qkv   = ws;              // 49152
    float* ctx   = ws + 49152;      // 16384
    float* apart = ws + 65536;      // 256*8*68 = 139264

    // q,k,v projections (single-pass GEMV, deterministic intra-wave reduce)
    gemv3<<<dim3(768), 256, 0, stream>>>(hs, Wq, Wk, Wv, bq, bk, bv, qkv);

    // fused cache-copy + flash-decode attention (nt loads, PLAIN stores)
    attn_fused<<<dim3(256, NCHUNK), 256, 0, stream>>>(qkv, pk, pv, mask,
                                                      kout, vout, apart);
    // fix row pos (cache + partials) and merge chunks
    merge_fix<<<dim3(256), 64, 0, stream>>>(qkv, pk, pv, mask, cpos,
                                            kout, vout, apart, ctx);

    // output projection
    gemv3<<<dim3(256), 256, 0, stream>>>(ctx, Wo, Wo, Wo, bo, bo, bo, out_attn);
}